// Round 5
// baseline (340.320 us; speedup 1.0000x reference)
//
#include <hip/hip_runtime.h>
#include <hip/hip_bf16.h>
#include <math.h>

// Problem constants (match reference)
#define B_  4096
#define D_  1024
#define H_  2048
#define C_  1000
#define T_  819200
#define F_  32
#define NPAD2 1024   // W2 rows padded 1000 -> 1024 (row 1000 = Ws, scalar head fused)
#define NPART 1024   // loss partial blocks (B_/4)

typedef __attribute__((ext_vector_type(8))) short short8;
typedef __attribute__((ext_vector_type(4))) float f32x4;

// ---------------- workspace layout (bytes) ----------------
static const size_t WS_SUMS     = 0;                               // B*F f32 = 512K
static const size_t WS_COUNTS   = WS_SUMS + (size_t)B_ * F_ * 4;   // B f32 = 16K
static const size_t WS_ZERO_SZ  = WS_COUNTS + (size_t)B_ * 4;      // zeroed each launch
static const size_t WS_PV       = WS_ZERO_SZ;                      // NPART f32
static const size_t WS_PA       = WS_PV + NPART * 4;
static const size_t WS_PS       = WS_PA + NPART * 4;
static const size_t WS_B2P      = WS_PS + NPART * 4;               // NPAD2 f32 padded bias
static const size_t WS_COMBINED = 1u << 20;                        // B*D bf16 = 8 MiB
static const size_t WS_W1BF     = WS_COMBINED + (size_t)B_ * D_ * 2;   // 4 MiB
static const size_t WS_W2BF     = WS_W1BF + (size_t)H_ * D_ * 2;       // 4 MiB
static const size_t WS_HIDDEN   = WS_W2BF + (size_t)NPAD2 * H_ * 2;    // B*H bf16 = 16 MiB
static const size_t WS_LOGITS   = WS_HIDDEN + (size_t)B_ * H_ * 2;     // B*NPAD2 f32 = 16 MiB

// ---------------- segment mean: run-length reduce, 8-row batches ----------
// 8 lanes (4 cols each) per row-group walk RPT consecutive rows in chunks of
// 8: 10 loads issued back-to-back per chunk (MLP), sorted-ids fast path
// (s[0]==s[7] => uniform chunk). Atomics only at segment transitions.
#define RPT 32
__global__ __launch_bounds__(256) void seg_reduce_kernel(
    const float* __restrict__ var_flat, const int* __restrict__ seg_ids,
    float* __restrict__ sums, float* __restrict__ counts) {
  int gt  = blockIdx.x * 256 + threadIdx.x;
  int c4  = (gt & 7) * 4;
  long base = (long)(gt >> 3) * RPT;
  int cur = -1;
  float a0 = 0.f, a1 = 0.f, a2 = 0.f, a3 = 0.f, cnt = 0.f;
#define FLUSH_SEG()                                              \
  if (cur >= 0) {                                                \
    float* dst = &sums[(size_t)cur * F_ + c4];                   \
    atomicAdd(dst + 0, a0); atomicAdd(dst + 1, a1);              \
    atomicAdd(dst + 2, a2); atomicAdd(dst + 3, a3);              \
    if (c4 == 0) atomicAdd(&counts[cur], cnt);                   \
    a0 = a1 = a2 = a3 = 0.f; cnt = 0.f;                          \
  }
  for (int rr = 0; rr < RPT; rr += 8) {
    int4 sa = *(const int4*)(seg_ids + base + rr);
    int4 sb = *(const int4*)(seg_ids + base + rr + 4);
    float4 v[8];
#pragma unroll
    for (int e = 0; e < 8; ++e)
      v[e] = *(const float4*)(var_flat + (base + rr + e) * F_ + c4);
    int s[8] = {sa.x, sa.y, sa.z, sa.w, sb.x, sb.y, sb.z, sb.w};
    if (s[0] == s[7]) {            // sorted => whole chunk is one segment
      if (s[0] != cur) { FLUSH_SEG(); cur = s[0]; }
#pragma unroll
      for (int e = 0; e < 8; ++e) {
        a0 += v[e].x; a1 += v[e].y; a2 += v[e].z; a3 += v[e].w;
      }
      cnt += 8.f;
    } else {
#pragma unroll
      for (int e = 0; e < 8; ++e) {
        if (s[e] != cur) { FLUSH_SEG(); cur = s[e]; }
        a0 += v[e].x; a1 += v[e].y; a2 += v[e].z; a3 += v[e].w; cnt += 1.f;
      }
    }
  }
  FLUSH_SEG();
#undef FLUSH_SEG
}

// ---------------- fp32 -> bf16 weight conversion ----------------
__global__ __launch_bounds__(256) void cvt_bf16_kernel(
    const float* __restrict__ src, __hip_bfloat16* __restrict__ dst, int n8) {
  int i = blockIdx.x * 256 + threadIdx.x;
  if (i >= n8) return;
  size_t off = (size_t)i * 8;
  float4 a = *(const float4*)(src + off);
  float4 b = *(const float4*)(src + off + 4);
  __hip_bfloat16 t[8];
  t[0] = __float2bfloat16(a.x); t[1] = __float2bfloat16(a.y);
  t[2] = __float2bfloat16(a.z); t[3] = __float2bfloat16(a.w);
  t[4] = __float2bfloat16(b.x); t[5] = __float2bfloat16(b.y);
  t[6] = __float2bfloat16(b.z); t[7] = __float2bfloat16(b.w);
  *(uint4*)(dst + off) = *(uint4*)t;
}

// W2 [C_,H_] fp32 + Ws [1,H_] -> padded [NPAD2,H_] bf16
__global__ __launch_bounds__(256) void cvt_w2_kernel(
    const float* __restrict__ W2, const float* __restrict__ Ws,
    __hip_bfloat16* __restrict__ dst) {
  int i = blockIdx.x * 256 + threadIdx.x;
  size_t off = (size_t)i * 8;
  int row = (int)(off / H_);
  __hip_bfloat16 t[8];
  const float* src = nullptr;
  if (row < C_)       src = W2 + off;
  else if (row == C_) src = Ws + (off - (size_t)C_ * H_);
  if (src) {
    float4 a = *(const float4*)(src);
    float4 b = *(const float4*)(src + 4);
    t[0] = __float2bfloat16(a.x); t[1] = __float2bfloat16(a.y);
    t[2] = __float2bfloat16(a.z); t[3] = __float2bfloat16(a.w);
    t[4] = __float2bfloat16(b.x); t[5] = __float2bfloat16(b.y);
    t[6] = __float2bfloat16(b.z); t[7] = __float2bfloat16(b.w);
  } else {
    for (int e = 0; e < 8; ++e) t[e] = __float2bfloat16(0.f);
  }
  *(uint4*)(dst + off) = *(uint4*)t;
}

// padded bias: b2p[0..999]=b2, [1000]=bs, rest 0
__global__ __launch_bounds__(256) void pad_bias_kernel(
    const float* __restrict__ b2, const float* __restrict__ bs,
    float* __restrict__ b2p) {
  int i = blockIdx.x * 256 + threadIdx.x;
  float v = 0.f;
  if (i < C_) v = b2[i];
  else if (i == C_) v = bs[0];
  b2p[i] = v;
}

// ---------------- combined = feature + means @ Wv^T + bv (bf16 out) -------
__global__ __launch_bounds__(256) void combined_kernel(
    const float* __restrict__ feat, const float* __restrict__ sums,
    const float* __restrict__ counts, const float* __restrict__ Wv,
    const float* __restrict__ bv, __hip_bfloat16* __restrict__ combined) {
  __shared__ float m[8][F_];
  int b0  = blockIdx.y * 8;
  int tid = threadIdx.x;
  {
    int seg = tid >> 5, col = tid & 31;
    float c = counts[b0 + seg];
    c = c < 1.f ? 1.f : c;
    m[seg][col] = sums[(size_t)(b0 + seg) * F_ + col] / c;
  }
  __syncthreads();
  int d = blockIdx.x * 256 + tid;
  float w[F_];
  {
    const float4* wv = (const float4*)(Wv + (size_t)d * F_);
#pragma unroll
    for (int f4 = 0; f4 < F_ / 4; ++f4) {
      float4 x = wv[f4];
      w[f4 * 4 + 0] = x.x; w[f4 * 4 + 1] = x.y;
      w[f4 * 4 + 2] = x.z; w[f4 * 4 + 3] = x.w;
    }
  }
  float bvd = bv[d];
#pragma unroll
  for (int bb = 0; bb < 8; ++bb) {
    float acc = feat[(size_t)(b0 + bb) * D_ + d] + bvd;
#pragma unroll
    for (int f = 0; f < F_; ++f) acc = fmaf(m[bb][f], w[f], acc);
    combined[(size_t)(b0 + bb) * D_ + d] = __float2bfloat16(acc);
  }
}

// ---------------- MFMA bf16 GEMM, 64x128 tile, double-buffered LDS --------
// C = A @ B^T + bias. BM=64, BN=128, BK=32, 256 thr (4 waves, 2x2 of 32x64
// wave-tiles). Small tile -> 4x more blocks than 128-square: latency hiding
// via TLP (grid was the occupancy cap at 10%).
__device__ inline void load16_lds(const short* g, short* l) {
  __builtin_amdgcn_global_load_lds(
      (const __attribute__((address_space(1))) void*)g,
      (__attribute__((address_space(3))) void*)l, 16, 0, 0);
}

template <int MODE>  // 0: relu + bf16 out; 1: f32 out (no mask, stride Nout)
__global__ __launch_bounds__(256) void gemm_mfma_kernel(
    const short* __restrict__ A, const short* __restrict__ Bm,
    const float* __restrict__ bias, void* __restrict__ Cout,
    int M, int K, int Nout) {
  __shared__ short As[2][2048];  // 2 x 4 KB  (64 rows x 32 k)
  __shared__ short Bs[2][4096];  // 2 x 8 KB  (128 rows x 32 k)
  const int tid  = threadIdx.x;
  const int lane = tid & 63;
  const int w    = tid >> 6;
  const int bm = blockIdx.y * 64;
  const int bn = blockIdx.x * 128;
  const int wm = (w >> 1) * 32;
  const int wn = (w & 1) * 64;
  const int m_lane = lane & 15;
  const int quad   = lane >> 4;

  f32x4 acc[2][4];
#pragma unroll
  for (int i = 0; i < 2; ++i)
#pragma unroll
    for (int j = 0; j < 4; ++j) acc[i][j] = f32x4{0.f, 0.f, 0.f, 0.f};

  // A: 256 16B-chunks/tile; thread tid stages chunk tid (kc=w, row=lane).
  const short* gA = A + (size_t)(bm + lane) * K + w * 8;
  // B: 512 chunks; wave w stages kc=w, rows lane and lane+64.
  const int cb0 = w * 128 + lane;
  const int cb1 = cb0 + 64;
  const short* gB0 = Bm + (size_t)(bn + (cb0 & 127)) * K + w * 8;
  const short* gB1 = Bm + (size_t)(bn + (cb1 & 127)) * K + w * 8;
  const int lA = w * 512;        // wave-uniform LDS bases (shorts)
  const int lB0 = w * 1024;
  const int lB1 = lB0 + 512;

  // prologue: stage chunk 0 into buf 0
  load16_lds(gA,  &As[0][lA]);
  load16_lds(gB0, &Bs[0][lB0]);
  load16_lds(gB1, &Bs[0][lB1]);

  const int iters = K >> 5;
  for (int it = 0; it < iters; ++it) {
    const int cur = it & 1, nxt = cur ^ 1;
    __syncthreads();   // drains buf[cur] staging; guards buf[nxt] reuse
    const int k1 = (it + 1) << 5;
    if (k1 < K) {
      load16_lds(gA + k1,  &As[nxt][lA]);
      load16_lds(gB0 + k1, &Bs[nxt][lB0]);
      load16_lds(gB1 + k1, &Bs[nxt][lB1]);
    }
    short8 af[2], bf[4];
#pragma unroll
    for (int i = 0; i < 2; ++i)
      af[i] = *(const short8*)&As[cur][quad * 512 + (wm + i * 16 + m_lane) * 8];
#pragma unroll
    for (int j = 0; j < 4; ++j)
      bf[j] = *(const short8*)&Bs[cur][quad * 1024 + (wn + j * 16 + m_lane) * 8];
#pragma unroll
    for (int i = 0; i < 2; ++i)
#pragma unroll
      for (int j = 0; j < 4; ++j)
        acc[i][j] = __builtin_amdgcn_mfma_f32_16x16x32_bf16(af[i], bf[j], acc[i][j], 0, 0, 0);
  }

  // epilogue: C/D layout col=lane&15, row=quad*4+reg
  const int row0 = bm + wm + quad * 4;
  const int col0 = bn + wn + m_lane;
  if (MODE == 0) {
    __hip_bfloat16* Cb = (__hip_bfloat16*)Cout;
#pragma unroll
    for (int j = 0; j < 4; ++j) {
      int col = col0 + j * 16;
      float bsv = bias[col];
#pragma unroll
      for (int i = 0; i < 2; ++i)
#pragma unroll
        for (int r = 0; r < 4; ++r) {
          int row = row0 + i * 16 + r;
          float v = acc[i][j][r] + bsv;
          v = v > 0.f ? v : 0.f;
          Cb[(size_t)row * Nout + col] = __float2bfloat16(v);
        }
    }
  } else {
    float* Cf = (float*)Cout;
#pragma unroll
    for (int j = 0; j < 4; ++j) {
      int col = col0 + j * 16;
      float bsv = bias[col];
#pragma unroll
      for (int i = 0; i < 2; ++i)
#pragma unroll
        for (int r = 0; r < 4; ++r) {
          int row = row0 + i * 16 + r;
          Cf[(size_t)row * Nout + col] = acc[i][j][r] + bsv;
        }
    }
  }
}

// ------- fused loss: softmax CE + accuracy + scalar MSE (col 1000) --------
__global__ __launch_bounds__(256) void loss_kernel(
    const float* __restrict__ logits, const int* __restrict__ target,
    const float* __restrict__ tgt_scal,
    float* __restrict__ pv, float* __restrict__ pa, float* __restrict__ ps) {
  int tid  = threadIdx.x;
  int lane = tid & 63;
  int w    = tid >> 6;
  int b    = blockIdx.x * 4 + w;
  const float*  row  = logits + (size_t)b * NPAD2;
  const float4* row4 = (const float4*)row;
  float v[16];
  float vmax = -INFINITY;
  int   imax = 0x7fffffff;
#pragma unroll
  for (int k = 0; k < 4; ++k) {
    int c4 = lane + 64 * k;
    float4 x = row4[c4];
    float e0 = x.x, e1 = x.y, e2 = x.z, e3 = x.w;
    int idx = c4 * 4;
    if (idx + 0 >= C_) e0 = -INFINITY;
    if (idx + 1 >= C_) e1 = -INFINITY;
    if (idx + 2 >= C_) e2 = -INFINITY;
    if (idx + 3 >= C_) e3 = -INFINITY;
    v[k * 4 + 0] = e0; v[k * 4 + 1] = e1; v[k * 4 + 2] = e2; v[k * 4 + 3] = e3;
    if (e0 > vmax) { vmax = e0; imax = idx + 0; }
    if (e1 > vmax) { vmax = e1; imax = idx + 1; }
    if (e2 > vmax) { vmax = e2; imax = idx + 2; }
    if (e3 > vmax) { vmax = e3; imax = idx + 3; }
  }
#pragma unroll
  for (int o = 32; o > 0; o >>= 1) {
    float ov = __shfl_down(vmax, o, 64);
    int   oi = __shfl_down(imax, o, 64);
    if (ov > vmax || (ov == vmax && oi < imax)) { vmax = ov; imax = oi; }
  }
  vmax = __shfl(vmax, 0, 64);
  float se = 0.f;
#pragma unroll
  for (int j = 0; j < 16; ++j) se += expf(v[j] - vmax);
#pragma unroll
  for (int o = 32; o > 0; o >>= 1) se += __shfl_down(se, o, 64);
  __shared__ float s_nll[4], s_acc[4], s_sq[4];
  if (lane == 0) {
    int t = target[b];
    float logp = row[t] - vmax - logf(se);
    s_nll[w] = -logp;
    s_acc[w] = (imax == t) ? 1.f : 0.f;
    float d = row[C_] - tgt_scal[b];     // fused scalar head output
    s_sq[w] = d * d;
  }
  __syncthreads();
  if (tid == 0) {
    pv[blockIdx.x] = s_nll[0] + s_nll[1] + s_nll[2] + s_nll[3];
    pa[blockIdx.x] = s_acc[0] + s_acc[1] + s_acc[2] + s_acc[3];
    ps[blockIdx.x] = s_sq[0] + s_sq[1] + s_sq[2] + s_sq[3];
  }
}

// ---------------- finalize: reduce partials ----------------
__global__ __launch_bounds__(256) void finalize_kernel(
    const float* __restrict__ pv, const float* __restrict__ pa,
    const float* __restrict__ ps, float* __restrict__ out) {
  int tid  = threadIdx.x;
  int lane = tid & 63;
  int w    = tid >> 6;
  float nll = 0.f, acc = 0.f, sq = 0.f;
  for (int i = tid; i < NPART; i += 256) {
    nll += pv[i]; acc += pa[i]; sq += ps[i];
  }
#pragma unroll
  for (int o = 32; o > 0; o >>= 1) {
    nll += __shfl_down(nll, o, 64);
    acc += __shfl_down(acc, o, 64);
    sq  += __shfl_down(sq,  o, 64);
  }
  __shared__ float sn[4], sa[4], ss[4];
  if (lane == 0) { sn[w] = nll; sa[w] = acc; ss[w] = sq; }
  __syncthreads();
  if (tid == 0) {
    float lv = (sn[0] + sn[1] + sn[2] + sn[3]) * (1.f / B_);
    float ls = (ss[0] + ss[1] + ss[2] + ss[3]) * (1.f / B_);
    float ac = (sa[0] + sa[1] + sa[2] + sa[3]) * (1.f / B_);
    out[0] = lv + ls;
    out[1] = lv;
    out[2] = ls;
    out[3] = ac;
  }
}

extern "C" void kernel_launch(void* const* d_in, const int* in_sizes, int n_in,
                              void* d_out, int out_size, void* d_ws, size_t ws_size,
                              hipStream_t stream) {
  const float* feature  = (const float*)d_in[0];
  const float* var_flat = (const float*)d_in[1];
  const int*   seg_ids  = (const int*)d_in[2];
  const int*   tgt_vec  = (const int*)d_in[3];
  const float* tgt_scal = (const float*)d_in[4];
  const float* Wv = (const float*)d_in[5];
  const float* bv = (const float*)d_in[6];
  const float* W1 = (const float*)d_in[7];
  const float* b1 = (const float*)d_in[8];
  const float* W2 = (const float*)d_in[9];
  const float* b2 = (const float*)d_in[10];
  const float* Ws = (const float*)d_in[11];
  const float* bs = (const float*)d_in[12];
  float* out = (float*)d_out;

  char* ws = (char*)d_ws;
  float* sums   = (float*)(ws + WS_SUMS);
  float* counts = (float*)(ws + WS_COUNTS);
  float* pv     = (float*)(ws + WS_PV);
  float* pa     = (float*)(ws + WS_PA);
  float* ps     = (float*)(ws + WS_PS);
  float* b2p    = (float*)(ws + WS_B2P);
  __hip_bfloat16* combined_bf = (__hip_bfloat16*)(ws + WS_COMBINED);
  __hip_bfloat16* W1bf        = (__hip_bfloat16*)(ws + WS_W1BF);
  __hip_bfloat16* W2bf        = (__hip_bfloat16*)(ws + WS_W2BF);
  __hip_bfloat16* hidden_bf   = (__hip_bfloat16*)(ws + WS_HIDDEN);
  float*          logits      = (float*)(ws + WS_LOGITS);

  hipMemsetAsync(ws, 0, WS_ZERO_SZ, stream);

  // 1) segment sums/counts (8-row batched, sorted fast path)
  seg_reduce_kernel<<<(T_ / RPT) * 8 / 256, 256, 0, stream>>>(var_flat, seg_ids, sums, counts);

  // 2) weight conversions (+ scalar-head fusion into W2/bias)
  cvt_bf16_kernel<<<(H_ * D_ / 8 + 255) / 256, 256, 0, stream>>>(W1, W1bf, H_ * D_ / 8);
  cvt_w2_kernel<<<(NPAD2 * H_ / 8) / 256, 256, 0, stream>>>(W2, Ws, W2bf);
  pad_bias_kernel<<<NPAD2 / 256, 256, 0, stream>>>(b2, bs, b2p);

  // 3) combined = feature + means @ Wv^T + bv  (bf16, 8 rows/block)
  {
    dim3 grid(D_ / 256, B_ / 8);
    combined_kernel<<<grid, 256, 0, stream>>>(feature, sums, counts, Wv, bv, combined_bf);
  }

  // 4) hidden = relu(combined @ W1^T + b1)  [4096 x 2048] bf16, MFMA dbuf
  {
    dim3 grid(H_ / 128, B_ / 64);     // 16 x 64 = 1024 blocks (4/CU)
    gemm_mfma_kernel<0><<<grid, 256, 0, stream>>>(
        (const short*)combined_bf, (const short*)W1bf, b1, hidden_bf, B_, D_, H_);
  }

  // 5) logits[4096 x 1024] = hidden @ W2p^T + b2p (col 1000 = scalar head)
  {
    dim3 grid(NPAD2 / 128, B_ / 64);  // 8 x 64 = 512 blocks (2/CU)
    gemm_mfma_kernel<1><<<grid, 256, 0, stream>>>(
        (const short*)hidden_bf, (const short*)W2bf, b2p, logits, B_, H_, NPAD2);
  }

  // 6) fused CE + accuracy + scalar MSE (partials)
  loss_kernel<<<B_ / 4, 256, 0, stream>>>(logits, tgt_vec, tgt_scal, pv, pa, ps);

  // 7) finalize
  finalize_kernel<<<1, 256, 0, stream>>>(pv, pa, ps, out);
}

// Round 6
// 295.299 us; speedup vs baseline: 1.1525x; 1.1525x over previous
//
#include <hip/hip_runtime.h>
#include <hip/hip_bf16.h>
#include <math.h>

// Problem constants (match reference)
#define B_  4096
#define D_  1024
#define H_  2048
#define C_  1000
#define T_  819200
#define F_  32
#define NPAD2 1024   // W2 rows padded 1000 -> 1024 (row 1000 = Ws, scalar head fused)
#define NPART 1024   // loss partial blocks (B_/4)

typedef __attribute__((ext_vector_type(8))) short short8;
typedef __attribute__((ext_vector_type(4))) float f32x4;

// ---------------- workspace layout (bytes) ----------------
// MFMA operands live in "octet-major" layout: element (row, k) of an
// [Mrows x K] matrix is stored at [(k>>3)*Mrows*8 + row*8 + (k&7)].
// => any (64 rows x 8 k) chunk is 1 KB contiguous: one fully-coalesced
// global_load_lds_dwordx4 per wave, landing in LDS in kc-major order.
static const size_t WS_SUMS     = 0;                               // B*F f32 = 512K
static const size_t WS_COUNTS   = WS_SUMS + (size_t)B_ * F_ * 4;   // B f32 = 16K
static const size_t WS_ZERO_SZ  = WS_COUNTS + (size_t)B_ * 4;      // zeroed each launch
static const size_t WS_PV       = WS_ZERO_SZ;                      // NPART f32
static const size_t WS_PA       = WS_PV + NPART * 4;
static const size_t WS_PS       = WS_PA + NPART * 4;
static const size_t WS_B2P      = WS_PS + NPART * 4;               // NPAD2 f32 padded bias
static const size_t WS_COMBINED = 1u << 20;                        // B*D bf16 oct = 8 MiB
static const size_t WS_W1BF     = WS_COMBINED + (size_t)B_ * D_ * 2;   // 4 MiB oct
static const size_t WS_W2BF     = WS_W1BF + (size_t)H_ * D_ * 2;       // 4 MiB oct
static const size_t WS_HIDDEN   = WS_W2BF + (size_t)NPAD2 * H_ * 2;    // B*H bf16 oct = 16 MiB
static const size_t WS_LOGITS   = WS_HIDDEN + (size_t)B_ * H_ * 2;     // B*NPAD2 f32 = 16 MiB

// ---------------- segment mean: run-length reduce, 8-row batches ----------
#define RPT 32
__global__ __launch_bounds__(256) void seg_reduce_kernel(
    const float* __restrict__ var_flat, const int* __restrict__ seg_ids,
    float* __restrict__ sums, float* __restrict__ counts) {
  int gt  = blockIdx.x * 256 + threadIdx.x;
  int c4  = (gt & 7) * 4;
  long base = (long)(gt >> 3) * RPT;
  int cur = -1;
  float a0 = 0.f, a1 = 0.f, a2 = 0.f, a3 = 0.f, cnt = 0.f;
#define FLUSH_SEG()                                              \
  if (cur >= 0) {                                                \
    float* dst = &sums[(size_t)cur * F_ + c4];                   \
    atomicAdd(dst + 0, a0); atomicAdd(dst + 1, a1);              \
    atomicAdd(dst + 2, a2); atomicAdd(dst + 3, a3);              \
    if (c4 == 0) atomicAdd(&counts[cur], cnt);                   \
    a0 = a1 = a2 = a3 = 0.f; cnt = 0.f;                          \
  }
  for (int rr = 0; rr < RPT; rr += 8) {
    int4 sa = *(const int4*)(seg_ids + base + rr);
    int4 sb = *(const int4*)(seg_ids + base + rr + 4);
    float4 v[8];
#pragma unroll
    for (int e = 0; e < 8; ++e)
      v[e] = *(const float4*)(var_flat + (base + rr + e) * F_ + c4);
    int s[8] = {sa.x, sa.y, sa.z, sa.w, sb.x, sb.y, sb.z, sb.w};
    if (s[0] == s[7]) {            // sorted => whole chunk is one segment
      if (s[0] != cur) { FLUSH_SEG(); cur = s[0]; }
#pragma unroll
      for (int e = 0; e < 8; ++e) {
        a0 += v[e].x; a1 += v[e].y; a2 += v[e].z; a3 += v[e].w;
      }
      cnt += 8.f;
    } else {
#pragma unroll
      for (int e = 0; e < 8; ++e) {
        if (s[e] != cur) { FLUSH_SEG(); cur = s[e]; }
        a0 += v[e].x; a1 += v[e].y; a2 += v[e].z; a3 += v[e].w; cnt += 1.f;
      }
    }
  }
  FLUSH_SEG();
#undef FLUSH_SEG
}

// ---------------- W1 -> octet-major bf16 [D/8][H][8] ----------------
// block = 32 rows x 8 octets; reads 256B-contiguous, writes 512B-contiguous.
__global__ __launch_bounds__(256) void cvt_w1_oct_kernel(
    const float* __restrict__ W1, __hip_bfloat16* __restrict__ dst) {
  int tid = threadIdx.x;
  int d0 = blockIdx.x * 64;
  int n0 = blockIdx.y * 32;
  int n_l = tid >> 3, kc = tid & 7;
  int n = n0 + n_l;
  int dd = d0 + kc * 8;
  float4 a = *(const float4*)(W1 + (size_t)n * D_ + dd);
  float4 b = *(const float4*)(W1 + (size_t)n * D_ + dd + 4);
  __hip_bfloat16 t[8];
  t[0] = __float2bfloat16(a.x); t[1] = __float2bfloat16(a.y);
  t[2] = __float2bfloat16(a.z); t[3] = __float2bfloat16(a.w);
  t[4] = __float2bfloat16(b.x); t[5] = __float2bfloat16(b.y);
  t[6] = __float2bfloat16(b.z); t[7] = __float2bfloat16(b.w);
  *(uint4*)(dst + ((size_t)(blockIdx.x * 8 + kc) * H_ + n) * 8) = *(uint4*)t;
}

// ---------------- W2+Ws -> octet-major bf16 [H/8][NPAD2][8] ----------------
__global__ __launch_bounds__(256) void cvt_w2_oct_kernel(
    const float* __restrict__ W2, const float* __restrict__ Ws,
    __hip_bfloat16* __restrict__ dst) {
  int tid = threadIdx.x;
  int h0 = blockIdx.x * 64;
  int n0 = blockIdx.y * 32;
  int n_l = tid >> 3, kc = tid & 7;
  int n = n0 + n_l;
  int hh = h0 + kc * 8;
  float va[8] = {0.f, 0.f, 0.f, 0.f, 0.f, 0.f, 0.f, 0.f};
  const float* src = nullptr;
  if (n < C_)       src = W2 + (size_t)n * H_ + hh;
  else if (n == C_) src = Ws + hh;
  if (src) {
    float4 a = *(const float4*)(src);
    float4 b = *(const float4*)(src + 4);
    va[0] = a.x; va[1] = a.y; va[2] = a.z; va[3] = a.w;
    va[4] = b.x; va[5] = b.y; va[6] = b.z; va[7] = b.w;
  }
  __hip_bfloat16 t[8];
#pragma unroll
  for (int e = 0; e < 8; ++e) t[e] = __float2bfloat16(va[e]);
  *(uint4*)(dst + ((size_t)(blockIdx.x * 8 + kc) * NPAD2 + n) * 8) = *(uint4*)t;
}

// padded bias: b2p[0..999]=b2, [1000]=bs, rest 0
__global__ __launch_bounds__(256) void pad_bias_kernel(
    const float* __restrict__ b2, const float* __restrict__ bs,
    float* __restrict__ b2p) {
  int i = blockIdx.x * 256 + threadIdx.x;
  float v = 0.f;
  if (i < C_) v = b2[i];
  else if (i == C_) v = bs[0];
  b2p[i] = v;
}

// ------- combined = feature + means @ Wv^T + bv, octet-major bf16 out -----
// block = 32 b-rows x 8 octets (64 d). Wv tile + means staged in LDS (+1 pad).
__global__ __launch_bounds__(256) void combined_kernel(
    const float* __restrict__ feat, const float* __restrict__ sums,
    const float* __restrict__ counts, const float* __restrict__ Wv,
    const float* __restrict__ bv, __hip_bfloat16* __restrict__ comb_oct) {
  __shared__ float m_s[32][F_ + 1];
  __shared__ float wv_s[64][F_ + 1];
  int tid = threadIdx.x;
  int d0 = blockIdx.x * 64;
  int b0 = blockIdx.y * 32;
  {  // stage means (32 x 32)
    int b_l = tid >> 3, f4 = (tid & 7) * 4;
    float c = counts[b0 + b_l];
    c = c < 1.f ? 1.f : c;
    float4 s4 = *(const float4*)(sums + (size_t)(b0 + b_l) * F_ + f4);
    m_s[b_l][f4 + 0] = s4.x / c; m_s[b_l][f4 + 1] = s4.y / c;
    m_s[b_l][f4 + 2] = s4.z / c; m_s[b_l][f4 + 3] = s4.w / c;
  }
  {  // stage Wv tile (64 x 32)
    int r = tid >> 2, p = (tid & 3) * 8;
    float4 a = *(const float4*)(Wv + (size_t)(d0 + r) * F_ + p);
    float4 b = *(const float4*)(Wv + (size_t)(d0 + r) * F_ + p + 4);
    wv_s[r][p + 0] = a.x; wv_s[r][p + 1] = a.y; wv_s[r][p + 2] = a.z; wv_s[r][p + 3] = a.w;
    wv_s[r][p + 4] = b.x; wv_s[r][p + 5] = b.y; wv_s[r][p + 6] = b.z; wv_s[r][p + 7] = b.w;
  }
  __syncthreads();
  int b_l = tid >> 3, kc = tid & 7;
  int b = b0 + b_l;
  int dbase = d0 + kc * 8;
  float4 f0 = *(const float4*)(feat + (size_t)b * D_ + dbase);
  float4 f1 = *(const float4*)(feat + (size_t)b * D_ + dbase + 4);
  float4 v0 = *(const float4*)(bv + dbase);
  float4 v1 = *(const float4*)(bv + dbase + 4);
  float fv[8]  = {f0.x, f0.y, f0.z, f0.w, f1.x, f1.y, f1.z, f1.w};
  float bvv[8] = {v0.x, v0.y, v0.z, v0.w, v1.x, v1.y, v1.z, v1.w};
  __hip_bfloat16 outv[8];
#pragma unroll
  for (int e = 0; e < 8; ++e) {
    float acc = fv[e] + bvv[e];
    const float* wr = wv_s[kc * 8 + e];
#pragma unroll
    for (int f = 0; f < F_; ++f) acc = fmaf(m_s[b_l][f], wr[f], acc);
    outv[e] = __float2bfloat16(acc);
  }
  *(uint4*)(comb_oct + ((size_t)(blockIdx.x * 8 + kc) * B_ + b) * 8) = *(uint4*)outv;
}

// ---------------- MFMA bf16 GEMM, octet-major operands ----------------
// C = A @ B^T + bias. BM=64, BN=128, BK=32 (4 octets), 256 thr (4 waves,
// 2x2 wave-tiles of 32x64). A/B octet-major => each staging instruction is
// a fully-coalesced contiguous 1 KB global_load_lds_dwordx4.
__device__ inline void load16_lds(const short* g, short* l) {
  __builtin_amdgcn_global_load_lds(
      (const __attribute__((address_space(1))) void*)g,
      (__attribute__((address_space(3))) void*)l, 16, 0, 0);
}

template <int MODE>  // 0: relu, bf16 octet-major out [Nout/8][M][8]; 1: f32 row-major out
__global__ __launch_bounds__(256) void gemm_mfma_kernel(
    const short* __restrict__ A, const short* __restrict__ Bm,
    const float* __restrict__ bias, void* __restrict__ Cout,
    int M, int Nrows, int K, int Nout) {
  __shared__ short As[2][2048];  // 4 kc x 64 rows x 8
  __shared__ short Bs[2][4096];  // 4 kc x 128 rows x 8
  const int tid  = threadIdx.x;
  const int lane = tid & 63;
  const int w    = tid >> 6;
  const int bm = blockIdx.y * 64;
  const int bn = blockIdx.x * 128;
  const int wm = (w >> 1) * 32;
  const int wn = (w & 1) * 64;
  const int m_lane = lane & 15;
  const int quad   = lane >> 4;

  f32x4 acc[2][4];
#pragma unroll
  for (int i = 0; i < 2; ++i)
#pragma unroll
    for (int j = 0; j < 4; ++j) acc[i][j] = f32x4{0.f, 0.f, 0.f, 0.f};

  // wave w stages octet kc=w of the current 4-octet K-slab:
  //   A chunk: rows bm..bm+63   (1 KB contiguous)
  //   B chunks: rows bn..bn+63 and bn+64..bn+127 (2 x 1 KB contiguous)
  const size_t strideA = (size_t)M * 32;       // elements per 4-octet step
  const size_t strideB = (size_t)Nrows * 32;
  const short* gA  = A  + ((size_t)w * M + bm) * 8 + lane * 8;
  const short* gB0 = Bm + ((size_t)w * Nrows + bn) * 8 + lane * 8;
  const short* gB1 = gB0 + 64 * 8;
  const int lA  = w * 512;       // wave-uniform LDS bases (shorts)
  const int lB0 = w * 1024;
  const int lB1 = lB0 + 512;

  // prologue: stage slab 0 into buf 0
  load16_lds(gA,  &As[0][lA]);
  load16_lds(gB0, &Bs[0][lB0]);
  load16_lds(gB1, &Bs[0][lB1]);

  const int iters = K >> 5;
  for (int it = 0; it < iters; ++it) {
    const int cur = it & 1, nxt = cur ^ 1;
    __syncthreads();   // drains buf[cur] staging; guards buf[nxt] reuse
    if (it + 1 < iters) {
      load16_lds(gA + strideA,  &As[nxt][lA]);
      load16_lds(gB0 + strideB, &Bs[nxt][lB0]);
      load16_lds(gB1 + strideB, &Bs[nxt][lB1]);
      gA += strideA; gB0 += strideB; gB1 += strideB;
    }
    short8 af[2], bf[4];
#pragma unroll
    for (int i = 0; i < 2; ++i)
      af[i] = *(const short8*)&As[cur][quad * 512 + (wm + i * 16 + m_lane) * 8];
#pragma unroll
    for (int j = 0; j < 4; ++j)
      bf[j] = *(const short8*)&Bs[cur][quad * 1024 + (wn + j * 16 + m_lane) * 8];
#pragma unroll
    for (int i = 0; i < 2; ++i)
#pragma unroll
      for (int j = 0; j < 4; ++j)
        acc[i][j] = __builtin_amdgcn_mfma_f32_16x16x32_bf16(af[i], bf[j], acc[i][j], 0, 0, 0);
  }

  // epilogue: C/D layout col=lane&15, row=quad*4+reg
  const int row0 = bm + wm + quad * 4;
  const int col0 = bn + wn + m_lane;
  if (MODE == 0) {
    // bf16 octet-major out: element (row, col) at (col>>3)*M*8 + row*8 + (col&7)
    __hip_bfloat16* Cb = (__hip_bfloat16*)Cout;
#pragma unroll
    for (int j = 0; j < 4; ++j) {
      int col = col0 + j * 16;
      float bsv = bias[col];
      __hip_bfloat16* base = Cb + ((size_t)(col >> 3) * M) * 8 + (col & 7);
#pragma unroll
      for (int i = 0; i < 2; ++i)
#pragma unroll
        for (int r = 0; r < 4; ++r) {
          int row = row0 + i * 16 + r;
          float v = acc[i][j][r] + bsv;
          v = v > 0.f ? v : 0.f;
          base[(size_t)row * 8] = __float2bfloat16(v);
        }
    }
  } else {
    float* Cf = (float*)Cout;
#pragma unroll
    for (int j = 0; j < 4; ++j) {
      int col = col0 + j * 16;
      float bsv = bias[col];
#pragma unroll
      for (int i = 0; i < 2; ++i)
#pragma unroll
        for (int r = 0; r < 4; ++r) {
          int row = row0 + i * 16 + r;
          Cf[(size_t)row * Nout + col] = acc[i][j][r] + bsv;
        }
    }
  }
}

// ------- fused loss: softmax CE + accuracy + scalar MSE (col 1000) --------
__global__ __launch_bounds__(256) void loss_kernel(
    const float* __restrict__ logits, const int* __restrict__ target,
    const float* __restrict__ tgt_scal,
    float* __restrict__ pv, float* __restrict__ pa, float* __restrict__ ps) {
  int tid  = threadIdx.x;
  int lane = tid & 63;
  int w    = tid >> 6;
  int b    = blockIdx.x * 4 + w;
  const float*  row  = logits + (size_t)b * NPAD2;
  const float4* row4 = (const float4*)row;
  float v[16];
  float vmax = -INFINITY;
  int   imax = 0x7fffffff;
#pragma unroll
  for (int k = 0; k < 4; ++k) {
    int c4 = lane + 64 * k;
    float4 x = row4[c4];
    float e0 = x.x, e1 = x.y, e2 = x.z, e3 = x.w;
    int idx = c4 * 4;
    if (idx + 0 >= C_) e0 = -INFINITY;
    if (idx + 1 >= C_) e1 = -INFINITY;
    if (idx + 2 >= C_) e2 = -INFINITY;
    if (idx + 3 >= C_) e3 = -INFINITY;
    v[k * 4 + 0] = e0; v[k * 4 + 1] = e1; v[k * 4 + 2] = e2; v[k * 4 + 3] = e3;
    if (e0 > vmax) { vmax = e0; imax = idx + 0; }
    if (e1 > vmax) { vmax = e1; imax = idx + 1; }
    if (e2 > vmax) { vmax = e2; imax = idx + 2; }
    if (e3 > vmax) { vmax = e3; imax = idx + 3; }
  }
#pragma unroll
  for (int o = 32; o > 0; o >>= 1) {
    float ov = __shfl_down(vmax, o, 64);
    int   oi = __shfl_down(imax, o, 64);
    if (ov > vmax || (ov == vmax && oi < imax)) { vmax = ov; imax = oi; }
  }
  vmax = __shfl(vmax, 0, 64);
  float se = 0.f;
#pragma unroll
  for (int j = 0; j < 16; ++j) se += expf(v[j] - vmax);
#pragma unroll
  for (int o = 32; o > 0; o >>= 1) se += __shfl_down(se, o, 64);
  __shared__ float s_nll[4], s_acc[4], s_sq[4];
  if (lane == 0) {
    int t = target[b];
    float logp = row[t] - vmax - logf(se);
    s_nll[w] = -logp;
    s_acc[w] = (imax == t) ? 1.f : 0.f;
    float d = row[C_] - tgt_scal[b];     // fused scalar head output
    s_sq[w] = d * d;
  }
  __syncthreads();
  if (tid == 0) {
    pv[blockIdx.x] = s_nll[0] + s_nll[1] + s_nll[2] + s_nll[3];
    pa[blockIdx.x] = s_acc[0] + s_acc[1] + s_acc[2] + s_acc[3];
    ps[blockIdx.x] = s_sq[0] + s_sq[1] + s_sq[2] + s_sq[3];
  }
}

// ---------------- finalize: reduce partials ----------------
__global__ __launch_bounds__(256) void finalize_kernel(
    const float* __restrict__ pv, const float* __restrict__ pa,
    const float* __restrict__ ps, float* __restrict__ out) {
  int tid  = threadIdx.x;
  int lane = tid & 63;
  int w    = tid >> 6;
  float nll = 0.f, acc = 0.f, sq = 0.f;
  for (int i = tid; i < NPART; i += 256) {
    nll += pv[i]; acc += pa[i]; sq += ps[i];
  }
#pragma unroll
  for (int o = 32; o > 0; o >>= 1) {
    nll += __shfl_down(nll, o, 64);
    acc += __shfl_down(acc, o, 64);
    sq  += __shfl_down(sq,  o, 64);
  }
  __shared__ float sn[4], sa[4], ss[4];
  if (lane == 0) { sn[w] = nll; sa[w] = acc; ss[w] = sq; }
  __syncthreads();
  if (tid == 0) {
    float lv = (sn[0] + sn[1] + sn[2] + sn[3]) * (1.f / B_);
    float ls = (ss[0] + ss[1] + ss[2] + ss[3]) * (1.f / B_);
    float ac = (sa[0] + sa[1] + sa[2] + sa[3]) * (1.f / B_);
    out[0] = lv + ls;
    out[1] = lv;
    out[2] = ls;
    out[3] = ac;
  }
}

extern "C" void kernel_launch(void* const* d_in, const int* in_sizes, int n_in,
                              void* d_out, int out_size, void* d_ws, size_t ws_size,
                              hipStream_t stream) {
  const float* feature  = (const float*)d_in[0];
  const float* var_flat = (const float*)d_in[1];
  const int*   seg_ids  = (const int*)d_in[2];
  const int*   tgt_vec  = (const int*)d_in[3];
  const float* tgt_scal = (const float*)d_in[4];
  const float* Wv = (const float*)d_in[5];
  const float* bv = (const float*)d_in[6];
  const float* W1 = (const float*)d_in[7];
  const float* b1 = (const float*)d_in[8];
  const float* W2 = (const float*)d_in[9];
  const float* b2 = (const float*)d_in[10];
  const float* Ws = (const float*)d_in[11];
  const float* bs = (const float*)d_in[12];
  float* out = (float*)d_out;

  char* ws = (char*)d_ws;
  float* sums   = (float*)(ws + WS_SUMS);
  float* counts = (float*)(ws + WS_COUNTS);
  float* pv     = (float*)(ws + WS_PV);
  float* pa     = (float*)(ws + WS_PA);
  float* ps     = (float*)(ws + WS_PS);
  float* b2p    = (float*)(ws + WS_B2P);
  __hip_bfloat16* comb_oct = (__hip_bfloat16*)(ws + WS_COMBINED);
  __hip_bfloat16* W1oct    = (__hip_bfloat16*)(ws + WS_W1BF);
  __hip_bfloat16* W2oct    = (__hip_bfloat16*)(ws + WS_W2BF);
  __hip_bfloat16* hid_oct  = (__hip_bfloat16*)(ws + WS_HIDDEN);
  float*          logits   = (float*)(ws + WS_LOGITS);

  hipMemsetAsync(ws, 0, WS_ZERO_SZ, stream);

  // 1) segment sums/counts (8-row batched, sorted fast path)
  seg_reduce_kernel<<<(T_ / RPT) * 8 / 256, 256, 0, stream>>>(var_flat, seg_ids, sums, counts);

  // 2) weight conversions -> octet-major bf16 (+ scalar-head fusion)
  {
    dim3 g1(D_ / 64, H_ / 32);
    cvt_w1_oct_kernel<<<g1, 256, 0, stream>>>(W1, W1oct);
    dim3 g2(H_ / 64, NPAD2 / 32);
    cvt_w2_oct_kernel<<<g2, 256, 0, stream>>>(W2, Ws, W2oct);
    pad_bias_kernel<<<NPAD2 / 256, 256, 0, stream>>>(b2, bs, b2p);
  }

  // 3) combined = feature + means @ Wv^T + bv  (octet-major bf16)
  {
    dim3 grid(D_ / 64, B_ / 32);
    combined_kernel<<<grid, 256, 0, stream>>>(feature, sums, counts, Wv, bv, comb_oct);
  }

  // 4) hidden = relu(combined @ W1^T + b1), octet-major out
  {
    dim3 grid(H_ / 128, B_ / 64);     // 16 x 64 = 1024 blocks (4/CU)
    gemm_mfma_kernel<0><<<grid, 256, 0, stream>>>(
        (const short*)comb_oct, (const short*)W1oct, b1, hid_oct, B_, H_, D_, H_);
  }

  // 5) logits[4096 x 1024] = hidden @ W2p^T + b2p (col 1000 = scalar head)
  {
    dim3 grid(NPAD2 / 128, B_ / 64);  // 8 x 64 = 512 blocks (2/CU)
    gemm_mfma_kernel<1><<<grid, 256, 0, stream>>>(
        (const short*)hid_oct, (const short*)W2oct, b2p, logits, B_, NPAD2, H_, NPAD2);
  }

  // 6) fused CE + accuracy + scalar MSE (partials)
  loss_kernel<<<B_ / 4, 256, 0, stream>>>(logits, tgt_vec, tgt_scal, pv, pa, ps);

  // 7) finalize
  finalize_kernel<<<1, 256, 0, stream>>>(pv, pa, ps, out);
}